// Round 10
// baseline (412.188 us; speedup 1.0000x reference)
//
#include <hip/hip_runtime.h>

#define CH 30
#define CELLS 49
#define ROWF 1470          // floats per batch row
#define NPAIR 735          // float2 pairs per row
#define NQ4 735            // float4 quads per 2-row region
#define WPB 4              // waves per block
#define RPBLK 4            // rows per block = 2 regions x 2 rows
#define HITS 6             // quad-stripes per wave (half of a region)
#define DEPTH 3            // rotating prefetch depth (24 staging VGPRs)

__device__ __forceinline__ float waveReduce(float v) {
    #pragma unroll
    for (int o = 32; o > 0; o >>= 1) v += __shfl_xor(v, o, 64);
    return v;
}

// R10 = R3's proven 120.63us config (2 waves share a 2-row float4 region in
// alternating 64-quad stripes) + three conservative deltas:
//  1. depth-3 rotating prefetch (6 loads in flight/wave).
//  2. launch_bounds(256,4): 128-VGPR cap so staging can't be allocator-sunk
//     (R2 failure mode) while R3's hard 64 cap risked spill/serialization.
//  3. fused finalize: last block (atomic counter) sums the per-block partials
//     in fixed strided order (deterministic) -- kills the 2nd launch (~3.7us
//     of reduce + inter-kernel gap in a 120us budget).
// Session conclusion feeding this: read throughput plateaus at ~2.7 TB/s
// across 9 structures (hoist/rotate/gather/gload_lds/TLP); main's floor is
// ~33-35us for the inherent 92 MB read. The 2x41us harness fills are fixed.
__global__ __launch_bounds__(256, 4) void yolo_main(const float* __restrict__ pred,
                                                    const float* __restrict__ targ,
                                                    float* __restrict__ ws,
                                                    float* __restrict__ out,
                                                    unsigned int* __restrict__ cnt,
                                                    int B, int NB, float invB) {
    const int w = threadIdx.x >> 6;
    const int lane = threadIdx.x & 63;
    const int h = w & 1;                         // half (stripe parity / box row)
    const int g = w >> 1;                        // region within block
    const int r0 = blockIdx.x * RPBLK + g * 2;

    __shared__ float4 boxS[WPB][2 * CELLS];      // pred boxes xyxy (broadcast)
    __shared__ int clist[WPB][CELLS];
    __shared__ float sred[WPB][3];
    __shared__ int lastFlag;

    float cls = 0.f, objc = 0.f, coord = 0.f;

    if (r0 < B) {                                // wave-uniform
        const int nrows = (B - r0) >= 2 ? 2 : 1;
        const float* P = pred + (size_t)r0 * ROWF;
        const float* T = targ + (size_t)r0 * ROWF;
        unsigned long long m[2] = {0ull, 0ull};

        if (nrows == 2) {
            const float4* P4 = (const float4*)P;
            const float4* T4 = (const float4*)T;

            // ---- conf gathers first (ballot dependency chain) ----
            const int cl = lane < CELLS ? lane : CELLS - 1;
            const float conf0 = T[cl * CH + 4];
            const float conf1 = T[ROWF + cl * CH + 4];

            // ---- pipeline prologue: stripes for it=0..DEPTH-1 of this half ----
            float4 pv[DEPTH], tv[DEPTH];
            #pragma unroll
            for (int s = 0; s < DEPTH; ++s) {
                const int q = lane + (2 * s + h) * 64;
                const int qc = q < NQ4 ? q : NQ4 - 1;
                pv[s] = P4[qc];
                tv[s] = T4[qc];
            }

            m[0] = __ballot((lane < CELLS) && (conf0 > 0.f));
            m[1] = __ballot((lane < CELLS) && (conf1 > 0.f));

            // ---- depth-3 rotating pipeline over this wave's 6 stripes ----
            #pragma unroll
            for (int it = 0; it < HITS; ++it) {
                const int slot = it % DEPTH;      // static after full unroll
                const float4 pa = pv[slot];
                const float4 ta = tv[slot];
                if (it + DEPTH < HITS) {
                    const int qn = lane + (2 * (it + DEPTH) + h) * 64;
                    const int qc = qn < NQ4 ? qn : NQ4 - 1;
                    pv[slot] = P4[qc];
                    tv[slot] = T4[qc];
                }
                const int qq = lane + (2 * it + h) * 64;
                const bool valid = qq < NQ4;
                #pragma unroll
                for (int k = 0; k < 2; ++k) {
                    const int p = 2 * qq + k;            // pair idx in 2-row stream
                    const int row = p >= NPAIR ? 1 : 0;
                    const int pr = p - row * NPAIR;      // pair idx within row
                    const int cell = (pr * 17477) >> 18; // pr/15 (valid to 767)
                    const int ch0 = 2 * (pr - cell * 15);
                    const float wobj = (float)((m[row] >> cell) & 1ull);
                    const float px = k ? pa.z : pa.x;
                    const float py = k ? pa.w : pa.y;
                    const float tx = k ? ta.z : ta.x;
                    const float ty = k ? ta.w : ta.y;
                    const float dx = px - tx, dy = py - ty;
                    // class loss: channels 10..29, obj cells only
                    cls += (valid && ch0 >= 10) ? wobj * (dx * dx + dy * dy) : 0.f;
                    // noobj conf loss (x0.5 folded): ch4 (.x) + ch9 (.y)
                    const float nn = (ch0 == 4 ? dx * dx : 0.f)
                                   + (ch0 == 8 ? dy * dy : 0.f);
                    objc += valid ? 0.5f * (1.f - wobj) * nn : 0.f;
                }
            }

            // ---- box/IoU phase: this wave handles row h of its region ----
            const unsigned long long mask = m[h];
            const int nBox = 2 * __popcll(mask);
            if (nBox) {                                  // wave-uniform
                const float* Pr = P + h * ROWF;
                const float* Tr = T + h * ROWF;
                const bool isObj = (lane < CELLS) && ((mask >> lane) & 1ull);
                if (isObj) clist[w][__popcll(mask & ((1ull << lane) - 1ull))] = lane;

                for (int e = lane; e < nBox; e += 64) {
                    const int c = clist[w][e >> 1];
                    const float* pb = Pr + c * CH + (e & 1) * 5;
                    const float cx = pb[0], cy = pb[1], bw = pb[2], bh = pb[3];
                    boxS[w][e] = make_float4(cx - 0.5f * bw, cy - 0.5f * bh,
                                             cx + 0.5f * bw, cy + 0.5f * bh);
                }

                for (int e = lane; e < nBox; e += 64) {
                    const int c = clist[w][e >> 1];
                    const float* tb = Tr + c * CH + (e & 1) * 5;
                    const float tcx = tb[0], tcy = tb[1], tw = tb[2], th = tb[3];
                    const float tx1 = tcx - 0.5f * tw, ty1 = tcy - 0.5f * th;
                    const float tx2 = tcx + 0.5f * tw, ty2 = tcy + 0.5f * th;
                    const float ta2 = (tx2 - tx1) * (ty2 - ty1);
                    float maxiou = 0.f;
                    for (int i = 0; i < nBox; ++i) {
                        const float4 pb4 = boxS[w][i];   // uniform addr = broadcast
                        const float lx = fmaxf(pb4.x, tx1), ly = fmaxf(pb4.y, ty1);
                        const float rx = fminf(pb4.z, tx2), ry = fminf(pb4.w, ty2);
                        const float iw = fmaxf(rx - lx, 0.f), ih = fmaxf(ry - ly, 0.f);
                        const float inter = iw * ih;
                        const float pa2 = (pb4.z - pb4.x) * (pb4.w - pb4.y);
                        const float un = pa2 + ta2 - inter;
                        const float iou = inter / (un > 0.f ? un : 1.f);
                        maxiou = fmaxf(maxiou, iou);
                    }
                    if (maxiou != 0.f) {                 // cmask
                        const float* pb = Pr + c * CH + (e & 1) * 5;
                        const float dcx = pb[0] - tcx, dcy = pb[1] - tcy;
                        coord += dcx * dcx + dcy * dcy;
                        const float dw = sqrtf(pb[2]) - sqrtf(tw);
                        const float dh = sqrtf(pb[3]) - sqrtf(th);
                        coord += dw * dw + dh * dh;
                        const float dc = pb[4] - tb[4];
                        objc += dc * dc;
                    }
                }
            }
        } else if (h == 0) {
            // ---- fallback: single trailing row (never hit for B%4==0) ----
            const float2* P2 = (const float2*)P;
            const float2* T2 = (const float2*)T;
            const int cl = lane < CELLS ? lane : CELLS - 1;
            const float conf = T[cl * CH + 4];
            const bool isObj = (lane < CELLS) && (conf > 0.f);
            const unsigned long long mask = __ballot(isObj);
            for (int j = lane; j < NPAIR; j += 64) {
                const float2 pq = P2[j], tq = T2[j];
                const int cell = (j * 17477) >> 18;
                const int ch0 = 2 * (j - cell * 15);
                const float wobj = (float)((mask >> cell) & 1ull);
                const float dx = pq.x - tq.x, dy = pq.y - tq.y;
                cls += (ch0 >= 10) ? wobj * (dx * dx + dy * dy) : 0.f;
                const float nn = (ch0 == 4 ? dx * dx : 0.f)
                               + (ch0 == 8 ? dy * dy : 0.f);
                objc += 0.5f * (1.f - wobj) * nn;
            }
            const int nBox = 2 * __popcll(mask);
            if (nBox) {
                if (isObj) clist[w][__popcll(mask & ((1ull << lane) - 1ull))] = lane;
                for (int e = lane; e < nBox; e += 64) {
                    const int c = clist[w][e >> 1];
                    const float* pb = P + c * CH + (e & 1) * 5;
                    const float cx = pb[0], cy = pb[1], bw = pb[2], bh = pb[3];
                    boxS[w][e] = make_float4(cx - 0.5f * bw, cy - 0.5f * bh,
                                             cx + 0.5f * bw, cy + 0.5f * bh);
                }
                for (int e = lane; e < nBox; e += 64) {
                    const int c = clist[w][e >> 1];
                    const float* tb = T + c * CH + (e & 1) * 5;
                    const float tcx = tb[0], tcy = tb[1], tw = tb[2], th = tb[3];
                    const float tx1 = tcx - 0.5f * tw, ty1 = tcy - 0.5f * th;
                    const float tx2 = tcx + 0.5f * tw, ty2 = tcy + 0.5f * th;
                    const float ta2 = (tx2 - tx1) * (ty2 - ty1);
                    float maxiou = 0.f;
                    for (int i = 0; i < nBox; ++i) {
                        const float4 pb4 = boxS[w][i];
                        const float lx = fmaxf(pb4.x, tx1), ly = fmaxf(pb4.y, ty1);
                        const float rx = fminf(pb4.z, tx2), ry = fminf(pb4.w, ty2);
                        const float iw = fmaxf(rx - lx, 0.f), ih = fmaxf(ry - ly, 0.f);
                        const float inter = iw * ih;
                        const float pa2 = (pb4.z - pb4.x) * (pb4.w - pb4.y);
                        const float un = pa2 + ta2 - inter;
                        const float iou = inter / (un > 0.f ? un : 1.f);
                        maxiou = fmaxf(maxiou, iou);
                    }
                    if (maxiou != 0.f) {
                        const float* pb = P + c * CH + (e & 1) * 5;
                        const float dcx = pb[0] - tcx, dcy = pb[1] - tcy;
                        coord += dcx * dcx + dcy * dcy;
                        const float dw = sqrtf(pb[2]) - sqrtf(tw);
                        const float dh = sqrtf(pb[3]) - sqrtf(th);
                        coord += dw * dw + dh * dh;
                        const float dc = pb[4] - tb[4];
                        objc += dc * dc;
                    }
                }
            }
        }
    }

    // ---- wave reduce -> block partial (one barrier) ----
    cls = waveReduce(cls); objc = waveReduce(objc); coord = waveReduce(coord);
    if (lane == 0) { sred[w][0] = cls; sred[w][1] = objc; sred[w][2] = coord; }
    __syncthreads();
    if (threadIdx.x == 0) {
        float C = 0.f, O = 0.f, X = 0.f;
        #pragma unroll
        for (int k = 0; k < WPB; ++k) { C += sred[k][0]; O += sred[k][1]; X += sred[k][2]; }
        ws[blockIdx.x] = C;
        ws[NB + blockIdx.x] = O;
        ws[2 * NB + blockIdx.x] = X;
    }

    // ---- last-block finalize (deterministic fixed-order sum) ----
    __threadfence();                             // publish partial device-wide
    if (threadIdx.x == 0) {
        const unsigned int old = atomicAdd(cnt, 1u);
        lastFlag = (old == (unsigned int)(NB - 1));
    }
    __syncthreads();
    if (!lastFlag) return;
    __threadfence();                             // acquire others' partials

    float c = 0.f, o = 0.f, x = 0.f;
    for (int i = threadIdx.x; i < NB; i += 256) {
        c += __hip_atomic_load(&ws[i], __ATOMIC_RELAXED, __HIP_MEMORY_SCOPE_AGENT);
        o += __hip_atomic_load(&ws[NB + i], __ATOMIC_RELAXED, __HIP_MEMORY_SCOPE_AGENT);
        x += __hip_atomic_load(&ws[2 * NB + i], __ATOMIC_RELAXED, __HIP_MEMORY_SCOPE_AGENT);
    }
    c = waveReduce(c); o = waveReduce(o); x = waveReduce(x);
    __syncthreads();                             // sred reuse safe-point
    if (lane == 0) { sred[w][0] = c; sred[w][1] = o; sred[w][2] = x; }
    __syncthreads();
    if (threadIdx.x == 0) {
        float C = 0.f, O = 0.f, X = 0.f;
        #pragma unroll
        for (int k = 0; k < WPB; ++k) { C += sred[k][0]; O += sred[k][1]; X += sred[k][2]; }
        const float bcls = C * invB;
        const float bobj = O * invB;          // noobj*0.5 folded upstream
        const float bcoord = X * 5.0f * invB; // COORD_LAMBDA
        out[0] = bcls + bobj + bcoord;
        out[1] = bcls;
        out[2] = bobj;
        out[3] = bcoord;
    }
}

extern "C" void kernel_launch(void* const* d_in, const int* in_sizes, int n_in,
                              void* d_out, int out_size, void* d_ws, size_t ws_size,
                              hipStream_t stream) {
    const float* pred = (const float*)d_in[0];
    const float* targ = (const float*)d_in[1];
    float* ws = (float*)d_ws;
    float* out = (float*)d_out;
    const int B = in_sizes[0] / ROWF;
    const int NB = (B + RPBLK - 1) / RPBLK;
    unsigned int* cnt = (unsigned int*)((char*)d_ws + (size_t)3 * NB * sizeof(float));

    hipMemsetAsync(cnt, 0, sizeof(unsigned int), stream);
    yolo_main<<<NB, 256, 0, stream>>>(pred, targ, ws, out, cnt, B, NB,
                                      1.0f / (float)B);
}

// Round 11
// 133.841 us; speedup vs baseline: 3.0797x; 3.0797x over previous
//
#include <hip/hip_runtime.h>

#define CH 30
#define CELLS 49
#define ROWF 1470          // floats per batch row
#define WPB 2              // waves per block (128 threads), one row per wave
#define FULLI 22           // full 64-lane width-4 global_load_lds per tensor-row
#define TAILL 62           // active lanes in tail instr (1470 - 22*64)

__device__ __forceinline__ float waveReduce(float v) {
    #pragma unroll
    for (int o = 32; o > 0; o >>= 1) v += __shfl_xor(v, o, 64);
    return v;
}

// R11: cell-parallel consume. R9 proved the dense stream is VALU-issue bound
// (~2.5 index/mask ops per byte), not memory bound; R10 proved device-fence
// fusion is toxic on multi-XCD. Here: each wave stages its row (P+T, 11760 B)
// into LDS via 46 fire-and-forget width-4 global_load_lds (no VGPR dest, no
// allocator hazard), waits its own vmcnt(0) -- no barriers, waves fully
// independent -- then lane c consumes cell c's 30 channels from LDS as 15
// float2 reads. Channel positions are static register offsets: zero index
// math. cls = 10 sub/fma pairs (obj lanes), noobj = 2 (noobj lanes), boxes
// come from the same registers; IoU via per-wave boxS broadcast as before.
// 26.7 KB LDS/block -> 5 blocks/CU -> 10 waves/CU; consume ~2-3 us total so
// the kernel is a near-pure fetch stream.
__global__ __launch_bounds__(128) void yolo_main(const float* __restrict__ pred,
                                                 const float* __restrict__ targ,
                                                 float* __restrict__ ws, int B,
                                                 int NB) {
    const int w = threadIdx.x >> 6;
    const int lane = threadIdx.x & 63;
    const int r = blockIdx.x * WPB + w;

    __shared__ float stage[WPB][2][ROWF];    // [wave][P=0/T=1][row floats]
    __shared__ float4 boxS[WPB][2 * CELLS];  // pred boxes xyxy (broadcast reads)
    __shared__ float sred[WPB][3];

    float cls = 0.f, objc = 0.f, coord = 0.f;

    if (r < B) {                             // wave-uniform
        const float* P = pred + (size_t)r * ROWF;
        const float* T = targ + (size_t)r * ROWF;
        float* lP = &stage[w][0][0];
        float* lT = &stage[w][1][0];

        // ---- stage: 46 fire-and-forget global->LDS dword copies ----
        #pragma unroll
        for (int k = 0; k < FULLI; ++k) {
            __builtin_amdgcn_global_load_lds(
                (const __attribute__((address_space(1))) float*)(P + k * 64 + lane),
                (__attribute__((address_space(3))) float*)(lP + k * 64), 4, 0, 0);
            __builtin_amdgcn_global_load_lds(
                (const __attribute__((address_space(1))) float*)(T + k * 64 + lane),
                (__attribute__((address_space(3))) float*)(lT + k * 64), 4, 0, 0);
        }
        if (lane < TAILL) {
            __builtin_amdgcn_global_load_lds(
                (const __attribute__((address_space(1))) float*)(P + FULLI * 64 + lane),
                (__attribute__((address_space(3))) float*)(lP + FULLI * 64), 4, 0, 0);
            __builtin_amdgcn_global_load_lds(
                (const __attribute__((address_space(1))) float*)(T + FULLI * 64 + lane),
                (__attribute__((address_space(3))) float*)(lT + FULLI * 64), 4, 0, 0);
        }
        asm volatile("s_waitcnt vmcnt(0)" ::: "memory");  // this wave's row landed

        // ---- cell-parallel consume: lane c owns cell c's 30 channels ----
        const bool act = lane < CELLS;
        const int c = act ? lane : CELLS - 1;
        const float2* pc = (const float2*)(lP + c * CH);  // 30*4B stride, 8B aligned
        const float2* tc = (const float2*)(lT + c * CH);

        // pairs j cover channels {2j, 2j+1}; ch4=p[2].x, ch9=p[4].y
        float2 pA[15], tA[15];
        #pragma unroll
        for (int j = 0; j < 15; ++j) { pA[j] = pc[j]; tA[j] = tc[j]; }

        const bool isObj = act && (tA[2].x > 0.f);
        const unsigned long long m = __ballot(isObj);
        const int nBox = 2 * __popcll(m);

        if (act && !isObj) {                 // noobj conf loss (0.5 folded)
            const float d4 = pA[2].x - tA[2].x;
            const float d9 = pA[4].y - tA[4].y;
            objc += 0.5f * (d4 * d4 + d9 * d9);
        }

        if (isObj) {
            // class loss: channels 10..29 = pairs 5..14
            #pragma unroll
            for (int j = 5; j < 15; ++j) {
                const float dx = pA[j].x - tA[j].x;
                const float dy = pA[j].y - tA[j].y;
                cls += dx * dx + dy * dy;
            }
            // publish my 2 pred boxes (xyxy) at rank order
            const int rank = __popcll(m & ((1ull << lane) - 1ull));
            // box0: ch0-3 = pA[0].x,.y,pA[1].x,.y
            boxS[w][2 * rank] = make_float4(pA[0].x - 0.5f * pA[1].x,
                                            pA[0].y - 0.5f * pA[1].y,
                                            pA[0].x + 0.5f * pA[1].x,
                                            pA[0].y + 0.5f * pA[1].y);
            // box1: ch5-8 = pA[2].y,pA[3].x,pA[3].y,pA[4].x
            boxS[w][2 * rank + 1] = make_float4(pA[2].y - 0.5f * pA[3].y,
                                                pA[3].x - 0.5f * pA[4].x,
                                                pA[2].y + 0.5f * pA[3].y,
                                                pA[3].x + 0.5f * pA[4].x);
        }

        // ---- IoU for this lane's 2 target boxes over all pred boxes ----
        if (isObj) {
            #pragma unroll
            for (int s = 0; s < 2; ++s) {
                // target box s: ch 5s..5s+3, conf ch 5s+4
                const float tcx = s ? tA[2].y : tA[0].x;
                const float tcy = s ? tA[3].x : tA[0].y;
                const float tw  = s ? tA[3].y : tA[1].x;
                const float th  = s ? tA[4].x : tA[1].y;
                const float pcx = s ? pA[2].y : pA[0].x;
                const float pcy = s ? pA[3].x : pA[0].y;
                const float pw  = s ? pA[3].y : pA[1].x;
                const float ph  = s ? pA[4].x : pA[1].y;
                const float pcf = s ? pA[4].y : pA[2].x;
                const float tcf = s ? tA[4].y : tA[2].x;
                const float tx1 = tcx - 0.5f * tw, ty1 = tcy - 0.5f * th;
                const float tx2 = tcx + 0.5f * tw, ty2 = tcy + 0.5f * th;
                const float ta = (tx2 - tx1) * (ty2 - ty1);
                float maxiou = 0.f;
                for (int i = 0; i < nBox; ++i) {
                    const float4 pb4 = boxS[w][i];   // uniform addr = broadcast
                    const float lx = fmaxf(pb4.x, tx1), ly = fmaxf(pb4.y, ty1);
                    const float rx = fminf(pb4.z, tx2), ry = fminf(pb4.w, ty2);
                    const float iw = fmaxf(rx - lx, 0.f), ih = fmaxf(ry - ly, 0.f);
                    const float inter = iw * ih;
                    const float pa = (pb4.z - pb4.x) * (pb4.w - pb4.y);
                    const float un = pa + ta - inter;
                    const float iou = inter / (un > 0.f ? un : 1.f);
                    maxiou = fmaxf(maxiou, iou);
                }
                if (maxiou != 0.f) {                 // cmask
                    const float dcx = pcx - tcx, dcy = pcy - tcy;
                    coord += dcx * dcx + dcy * dcy;
                    const float dw = sqrtf(pw) - sqrtf(tw);
                    const float dh = sqrtf(ph) - sqrtf(th);
                    coord += dw * dw + dh * dh;
                    const float dc = pcf - tcf;
                    objc += dc * dc;
                }
            }
        }
    }

    // ---- wave reduce, then block reduce (one barrier), one triple per block ----
    cls = waveReduce(cls); objc = waveReduce(objc); coord = waveReduce(coord);
    if (lane == 0) { sred[w][0] = cls; sred[w][1] = objc; sred[w][2] = coord; }
    __syncthreads();
    if (threadIdx.x == 0) {
        float C = 0.f, O = 0.f, X = 0.f;
        #pragma unroll
        for (int k = 0; k < WPB; ++k) { C += sred[k][0]; O += sred[k][1]; X += sred[k][2]; }
        ws[blockIdx.x] = C;
        ws[NB + blockIdx.x] = O;
        ws[2 * NB + blockIdx.x] = X;
    }
}

__global__ __launch_bounds__(1024) void yolo_reduce(const float* __restrict__ ws,
                                                    float* __restrict__ out,
                                                    int NB, float invB) {
    const int tid = threadIdx.x;
    const int w = tid >> 6, lane = tid & 63;
    float c = 0.f, o = 0.f, x = 0.f;
    for (int i = tid; i < NB; i += 1024) {
        c += ws[i];
        o += ws[NB + i];
        x += ws[2 * NB + i];
    }
    c = waveReduce(c); o = waveReduce(o); x = waveReduce(x);
    __shared__ float sred[16][3];
    if (lane == 0) { sred[w][0] = c; sred[w][1] = o; sred[w][2] = x; }
    __syncthreads();
    if (tid == 0) {
        float C = 0.f, O = 0.f, X = 0.f;
        #pragma unroll
        for (int k = 0; k < 16; ++k) { C += sred[k][0]; O += sred[k][1]; X += sred[k][2]; }
        const float bcls = C * invB;
        const float bobj = O * invB;          // noobj*0.5 folded upstream
        const float bcoord = X * 5.0f * invB; // COORD_LAMBDA
        out[0] = bcls + bobj + bcoord;
        out[1] = bcls;
        out[2] = bobj;
        out[3] = bcoord;
    }
}

extern "C" void kernel_launch(void* const* d_in, const int* in_sizes, int n_in,
                              void* d_out, int out_size, void* d_ws, size_t ws_size,
                              hipStream_t stream) {
    const float* pred = (const float*)d_in[0];
    const float* targ = (const float*)d_in[1];
    float* ws = (float*)d_ws;
    float* out = (float*)d_out;
    const int B = in_sizes[0] / ROWF;
    const int NB = (B + WPB - 1) / WPB;

    yolo_main<<<NB, 128, 0, stream>>>(pred, targ, ws, B, NB);
    yolo_reduce<<<1, 1024, 0, stream>>>(ws, out, NB, 1.0f / (float)B);
}